// Round 12
// baseline (303.658 us; speedup 1.0000x reference)
//
#include <hip/hip_runtime.h>
#include <hip/hip_bf16.h>
#include <math.h>

#define N_NODES 50000
#define F_DIM 256
#define NE 1000000
#define N_HEADS 8
#define M_PAD 50048   // 128-row padded

typedef __attribute__((ext_vector_type(8))) short short8;   // 8 bf16 = 4 VGPRs
typedef __attribute__((ext_vector_type(4))) float floatx4;
typedef __attribute__((ext_vector_type(2))) float floatx2;

__device__ __forceinline__ void load16_lds(const void* g, void* l) {
    __builtin_amdgcn_global_load_lds(
        (const __attribute__((address_space(1))) unsigned int*)(unsigned long long)g,
        (__attribute__((address_space(3))) unsigned int*)(unsigned int)(unsigned long long)l,
        16, 0, 0);
}

__device__ __forceinline__ unsigned int pack2bf(float a, float b) {
    __hip_bfloat16 t0 = __float2bfloat16(a), t1 = __float2bfloat16(b);
    unsigned short u0, u1;
    __builtin_memcpy(&u0, &t0, 2);
    __builtin_memcpy(&u1, &t1, 2);
    return (unsigned int)u0 | ((unsigned int)u1 << 16);
}

__device__ __forceinline__ float bf_lo(unsigned int u) {
    return __uint_as_float(u << 16);
}
__device__ __forceinline__ float bf_hi(unsigned int u) {
    return __uint_as_float(u & 0xffff0000u);
}

// pack 4 fp32 -> 4 fp8 e4m3 (bytes 0..3), HW packed converters
__device__ __forceinline__ unsigned int pack4fp8(float x, float y, float z,
                                                 float w) {
    int v = __builtin_amdgcn_cvt_pk_fp8_f32(x, y, 0, false);   // bytes 0,1
    v = __builtin_amdgcn_cvt_pk_fp8_f32(z, w, v, true);        // bytes 2,3
    return (unsigned int)v;
}

// ---------------------------------------------------------------------------
// merged prep: blocks [0,12500) conv_x; [12500,16407) edata pack;
// [16407,17239) weight transpose+bf16; [17239,17435) row_start.
// ---------------------------------------------------------------------------
__global__ __launch_bounds__(256) void prep_kernel(
    const float* __restrict__ node_states, const int* __restrict__ edges,
    const float* __restrict__ ew, const float* __restrict__ Wp,
    const float* __restrict__ Wk, const float* __restrict__ Wo,
    __hip_bfloat16* __restrict__ xt16, int2* __restrict__ edata,
    __hip_bfloat16* __restrict__ wpT, __hip_bfloat16* __restrict__ wkT,
    __hip_bfloat16* __restrict__ woT, int* __restrict__ row_start) {
    const int b = blockIdx.x;
    const int tid = threadIdx.x;
    if (b < 12500) {                       // node_states -> bf16
        const size_t i = ((size_t)b * 256 + tid) * 4;
        const float4 v = *(const float4*)(node_states + i);
        uint2 pk;
        pk.x = pack2bf(v.x, v.y);
        pk.y = pack2bf(v.z, v.w);
        *(uint2*)((unsigned short*)xt16 + i) = pk;
    } else if (b < 16407) {                // {dst, ew} pack
        const int e = (b - 12500) * 256 + tid;
        if (e < NE) {
            int2 d;
            d.x = edges[2 * e + 1];
            d.y = __float_as_int(ew[e]);
            edata[e] = d;
        }
    } else if (b < 17239) {                // weights -> BT bf16
        const int wb = b - 16407;
        if (wb < 256) {
            int idx = wb * 256 + tid;          // 65536 = [n][k]
            int n = idx >> 8, k = idx & 255;
            wpT[idx] = __float2bfloat16(Wp[k * 256 + n]);
        } else if (wb < 768) {
            int idx = (wb - 256) * 256 + tid;  // 131072 = [l][n][k]
            int l = idx >> 16, n = (idx >> 8) & 255, k = idx & 255;
            int h = n >> 5, u = n & 31;
            wkT[idx] = __float2bfloat16(Wk[(((l * 8 + h) * 256) + k) * 32 + u]);
        } else {
            int idx = (wb - 768) * 256 + tid;  // 16384 = [n(64)][k(256)]
            int n = idx >> 8, k = idx & 255;
            woT[idx] = __float2bfloat16(Wo[k * 64 + n]);
        }
    } else {                               // row_start = lower_bound(src, i)
        const int i = (b - 17239) * 256 + tid;
        if (i > N_NODES) return;
        if (i == N_NODES) { row_start[N_NODES] = NE; return; }
        int lo = 0, hi = NE;
        while (lo < hi) {
            int mid = (lo + hi) >> 1;
            if (edges[2 * mid] < i) lo = mid + 1; else hi = mid;
        }
        row_start[i] = lo;
    }
}

// ---------------------------------------------------------------------------
// MFMA GEMM: Y[M x 256] = A16[M x 256] @ B (BT as [256 n][256 k] bf16)
// 128x128 tile, 4 waves (2x2), 16x16x32 bf16 MFMA, operands swapped so lane
// holds C[m = lane&15 + 16mt][n0 + (lane>>4)*4 + 16nt .. +3] -> packed stores.
// FP8OUT: Y is fp8 e4m3 (xt8); else bf16.
// ALPHA: also emit a_src/a_dst from the fp32 accumulators.
// ---------------------------------------------------------------------------
template <bool BIAS_RELU, bool FP8OUT, bool ALPHA>
__global__ __launch_bounds__(256) void gemm_mfma(
    const __hip_bfloat16* __restrict__ A16, const __hip_bfloat16* __restrict__ BT,
    const float* __restrict__ bias, void* __restrict__ Y,
    const float* __restrict__ Wa_l, float* __restrict__ a_srcO,
    float* __restrict__ a_dstO) {
    __shared__ __align__(16) short lA[128 * 32];
    __shared__ __align__(16) short lB[128 * 32];
    const int tid = threadIdx.x;
    const int row0 = blockIdx.x * 128;
    const int n0 = blockIdx.y * 128;
    const int w = tid >> 6, l = tid & 63;
    const int wr = w >> 1, wc = w & 1;

    const __hip_bfloat16* gA = A16 + (size_t)(row0 + (tid >> 2)) * 256 + (tid & 3) * 8;
    const __hip_bfloat16* gB = BT + (size_t)(n0 + (tid >> 2)) * 256 + (tid & 3) * 8;
    short* dA = lA + tid * 8;
    short* dB = lB + tid * 8;

    floatx4 acc[4][4] = {};

    const short* pa = lA + (wr * 64 + (l & 15)) * 32 + (l >> 4) * 8;
    const short* pb = lB + (wc * 64 + (l & 15)) * 32 + (l >> 4) * 8;

    for (int kk = 0; kk < 8; ++kk) {
        const int ko = kk * 32;
        load16_lds(gA + ko, dA);
        load16_lds(gA + 64 * 256 + ko, dA + 256 * 8);
        load16_lds(gB + ko, dB);
        load16_lds(gB + 64 * 256 + ko, dB + 256 * 8);
        __syncthreads();
        short8 af[4], bf[4];
#pragma unroll
        for (int t = 0; t < 4; ++t) {
            af[t] = *(const short8*)(pa + t * 16 * 32);
            bf[t] = *(const short8*)(pb + t * 16 * 32);
        }
#pragma unroll
        for (int mt = 0; mt < 4; ++mt)
#pragma unroll
            for (int nt = 0; nt < 4; ++nt)
                acc[mt][nt] = __builtin_amdgcn_mfma_f32_16x16x32_bf16(
                    bf[nt], af[mt], acc[mt][nt], 0, 0, 0);
        __syncthreads();
    }

    const int m_base = row0 + wr * 64 + (l & 15);
    const int n_base = n0 + wc * 64 + ((l >> 4) << 2);
#pragma unroll
    for (int mt = 0; mt < 4; ++mt) {
        const int m = m_base + mt * 16;
        if (m >= N_NODES) continue;
#pragma unroll
        for (int nt = 0; nt < 4; ++nt) {
            const int n = n_base + nt * 16;
            floatx4 v = acc[mt][nt];
            if (BIAS_RELU) {
                const float4 bb = *(const float4*)(bias + n);
                v.x = fmaxf(v.x + bb.x, 0.f);
                v.y = fmaxf(v.y + bb.y, 0.f);
                v.z = fmaxf(v.z + bb.z, 0.f);
                v.w = fmaxf(v.w + bb.w, 0.f);
            }
            if constexpr (FP8OUT) {
                *((unsigned int*)Y + ((((size_t)m << 8) + n) >> 2)) =
                    pack4fp8(v.x, v.y, v.z, v.w);
            } else {
                uint2 pk;
                pk.x = pack2bf(v.x, v.y);
                pk.y = pack2bf(v.z, v.w);
                *(uint2*)((unsigned short*)Y + ((size_t)m << 8) + n) = pk;
            }
        }
    }

    if constexpr (ALPHA) {
        const int lg = l >> 4;
        // u = (nt&1)*16 + lg*4 + j  for acc[mt][2*hl + (nt&1)] component j
        float4 wS[2][2], wD[2][2];
#pragma unroll
        for (int hl = 0; hl < 2; ++hl) {
            const int h = (n0 >> 5) + wc * 2 + hl;
#pragma unroll
            for (int p = 0; p < 2; ++p) {
                wS[hl][p] = *(const float4*)(Wa_l + h * 64 + p * 16 + lg * 4);
                wD[hl][p] =
                    *(const float4*)(Wa_l + h * 64 + 32 + p * 16 + lg * 4);
            }
        }
        float aS[4][2], aD[4][2];
#pragma unroll
        for (int mt = 0; mt < 4; ++mt)
#pragma unroll
            for (int hl = 0; hl < 2; ++hl) {
                float s = 0.f, d = 0.f;
#pragma unroll
                for (int p = 0; p < 2; ++p) {
                    const floatx4 v = acc[mt][2 * hl + p];
                    const float4 ws = wS[hl][p], wd = wD[hl][p];
                    s += v.x * ws.x + v.y * ws.y + v.z * ws.z + v.w * ws.w;
                    d += v.x * wd.x + v.y * wd.y + v.z * wd.z + v.w * wd.w;
                }
                s += __shfl_xor(s, 16);
                s += __shfl_xor(s, 32);
                d += __shfl_xor(d, 16);
                d += __shfl_xor(d, 32);
                aS[mt][hl] = s;
                aD[mt][hl] = d;
            }
        if (lg == 0) {   // lanes 0..15: one writer per (m, h)
#pragma unroll
            for (int mt = 0; mt < 4; ++mt) {
                const int m = m_base + mt * 16;   // < M_PAD (buffers padded)
#pragma unroll
                for (int hl = 0; hl < 2; ++hl) {
                    const int h = (n0 >> 5) + wc * 2 + hl;
                    a_srcO[(size_t)m * 8 + h] = aS[mt][hl];
                    a_dstO[(size_t)m * 8 + h] = aD[mt][hl];
                }
            }
        }
    }
}

// ---------------------------------------------------------------------------
// Final projection: out[M x 64] = xb16[M x 256] @ Wo + bo  (fp32 out)
// ---------------------------------------------------------------------------
__global__ __launch_bounds__(256) void gemm_mfma_out(
    const __hip_bfloat16* __restrict__ A16, const __hip_bfloat16* __restrict__ BT,
    const float* __restrict__ bias, float* __restrict__ out) {
    __shared__ __align__(16) short lA[128 * 32];
    __shared__ __align__(16) short lB[64 * 32];
    const int tid = threadIdx.x;
    const int row0 = blockIdx.x * 128;
    const int w = tid >> 6, l = tid & 63;

    const __hip_bfloat16* gA = A16 + (size_t)(row0 + (tid >> 2)) * 256 + (tid & 3) * 8;
    const __hip_bfloat16* gB = BT + (size_t)(tid >> 2) * 256 + (tid & 3) * 8;
    short* dA = lA + tid * 8;
    short* dB = lB + tid * 8;   // 256 threads * 8 shorts = exactly 64*32

    floatx4 acc[2][4] = {};

    const short* pa = lA + (w * 32 + (l & 15)) * 32 + (l >> 4) * 8;
    const short* pb = lB + (l & 15) * 32 + (l >> 4) * 8;

    for (int kk = 0; kk < 8; ++kk) {
        const int ko = kk * 32;
        load16_lds(gA + ko, dA);
        load16_lds(gA + 64 * 256 + ko, dA + 256 * 8);
        load16_lds(gB + ko, dB);
        __syncthreads();
        short8 af[2], bf[4];
#pragma unroll
        for (int t = 0; t < 2; ++t) af[t] = *(const short8*)(pa + t * 16 * 32);
#pragma unroll
        for (int t = 0; t < 4; ++t) bf[t] = *(const short8*)(pb + t * 16 * 32);
#pragma unroll
        for (int mt = 0; mt < 2; ++mt)
#pragma unroll
            for (int nt = 0; nt < 4; ++nt)
                acc[mt][nt] = __builtin_amdgcn_mfma_f32_16x16x32_bf16(
                    bf[nt], af[mt], acc[mt][nt], 0, 0, 0);
        __syncthreads();
    }

    const int m_base = row0 + w * 32 + (l & 15);
    const int n_base = (l >> 4) << 2;
#pragma unroll
    for (int mt = 0; mt < 2; ++mt) {
        const int m = m_base + mt * 16;
        if (m >= N_NODES) continue;
#pragma unroll
        for (int nt = 0; nt < 4; ++nt) {
            const int n = n_base + nt * 16;
            const float4 bb = *(const float4*)(bias + n);
            floatx4 v = acc[mt][nt];
            float4 o = {v.x + bb.x, v.y + bb.y, v.z + bb.z, v.w + bb.w};
            *(float4*)(&out[(size_t)m * 64 + n]) = o;
        }
    }
}

// ---------------------------------------------------------------------------
// fused score + aggregation, SIMT score phase + scalar-base gather phase:
//  - score lanes: (slot = l>>3, head = l&7) -> 8 edges' x 8 heads' scores in
//    one pass (1 edata VMEM + 1 a_dst VMEM per 8 edges, no 8x redundancy)
//  - ACC per edge j: d_j = v_readlane(ed, 8j) (SGPR base -> scalar
//    addressing, the R10 lesson), score via one ds_bpermute
//  - ssum: shfl_xor over slot bits + one bpermute head->feature space
// ---------------------------------------------------------------------------
__device__ __forceinline__ float edge_score(float asrc, float ad, float w) {
    float sp = (asrc + ad) * w;
    sp = (sp >= 0.f) ? sp : 0.2f * sp;    // leaky_relu(0.2)
    sp = fminf(fmaxf(sp, -2.f), 2.f);     // clip
    return __expf(sp);
}

#define ACC8(u, s)                                               \
    {                                                            \
        const floatx2 f01 = __builtin_amdgcn_cvt_pk_f32_fp8(u, false); \
        const floatx2 f23 = __builtin_amdgcn_cvt_pk_f32_fp8(u, true);  \
        a0 = fmaf(f01.x, s, a0);                                 \
        a1 = fmaf(f01.y, s, a1);                                 \
        a2 = fmaf(f23.x, s, a2);                                 \
        a3 = fmaf(f23.y, s, a3);                                 \
    }

__global__ __launch_bounds__(256) void edge_kernel(
    const unsigned long long* __restrict__ edata,
    const int* __restrict__ row_start, const unsigned int* __restrict__ xt8,
    const float* __restrict__ a_src, const float* __restrict__ a_dst,
    __hip_bfloat16* __restrict__ xb16) {
    const int tid = threadIdx.x;
    const int node =
        __builtin_amdgcn_readfirstlane(blockIdx.x * 4 + (tid >> 6));
    const int l = tid & 63;
    const int hf = l >> 3;     // feature-space head (features hf*32 + ...)
    const int hs = l & 7;      // score-space head
    const int slot = l >> 3;   // score-space edge slot
    const int e0 = __builtin_amdgcn_readfirstlane(row_start[node]);
    const int e1 = __builtin_amdgcn_readfirstlane(row_start[node + 1]);
    const float asrc = a_src[(size_t)node * 8 + hs];
    const int baddr = hf << 2;   // bpermute byte addr of lane hf

    // residual row (bf16), non-temporal: streamed once per node
    unsigned long long* xrow =
        (unsigned long long*)((unsigned short*)xb16 + (size_t)node * 256 +
                              l * 4);
    const unsigned long long xin = __builtin_nontemporal_load(xrow);

    float a0 = 0.f, a1 = 0.f, a2 = 0.f, a3 = 0.f, ssp = 0.f;
    int eb = e0;
    for (; eb + 8 <= e1; eb += 8) {
        const unsigned long long ed =
            __builtin_nontemporal_load(edata + eb + slot);
        const int dd = (int)(unsigned int)ed;
        const float w = __uint_as_float((unsigned int)(ed >> 32));
        const float s = edge_score(asrc, a_dst[(size_t)dd * 8 + hs], w);
        ssp += s;
        const int sbits = (int)__float_as_uint(s);
#pragma unroll
        for (int j = 0; j < 8; ++j) {
            const float sj = __uint_as_float(
                (unsigned int)__builtin_amdgcn_ds_bpermute(baddr + (j << 5),
                                                           sbits));
            const int dj = __builtin_amdgcn_readlane(dd, j * 8);
            const unsigned int u = xt8[(size_t)dj * 64 + l];
            ACC8(u, sj);
        }
    }
    if (eb < e1) {   // tail (< 8 edges)
        const int ecl = min(eb + slot, e1 - 1);
        const unsigned long long ed = __builtin_nontemporal_load(edata + ecl);
        const int dd = (int)(unsigned int)ed;
        const float w = __uint_as_float((unsigned int)(ed >> 32));
        float s = edge_score(asrc, a_dst[(size_t)dd * 8 + hs], w);
        s = (eb + slot < e1) ? s : 0.f;
        ssp += s;
        const int sbits = (int)__float_as_uint(s);
        const int jmax = e1 - eb;
        for (int j = 0; j < jmax; ++j) {
            const float sj = __uint_as_float(
                (unsigned int)__builtin_amdgcn_ds_bpermute(baddr + (j << 5),
                                                           sbits));
            const int dj = __builtin_amdgcn_readlane(dd, j * 8);
            const unsigned int u = xt8[(size_t)dj * 64 + l];
            ACC8(u, sj);
        }
    }
    // ssum: reduce over slots (lane bits 3,4,5), then head->feature space
    ssp += __shfl_xor(ssp, 8);
    ssp += __shfl_xor(ssp, 16);
    ssp += __shfl_xor(ssp, 32);
    const float ssum = __uint_as_float((unsigned int)__builtin_amdgcn_ds_bpermute(
        baddr, (int)__float_as_uint(ssp)));

    const float inv = (e1 > e0) ? 1.f / ssum : 0.f;
    // residual add in fp32, round once to bf16
    const unsigned int xlo = (unsigned int)xin;
    const unsigned int xhi = (unsigned int)(xin >> 32);
    const float c0 = bf_lo(xlo) + fmaxf(a0 * inv, 0.f);
    const float c1 = bf_hi(xlo) + fmaxf(a1 * inv, 0.f);
    const float c2 = bf_lo(xhi) + fmaxf(a2 * inv, 0.f);
    const float c3 = bf_hi(xhi) + fmaxf(a3 * inv, 0.f);
    const unsigned long long pk =
        (unsigned long long)pack2bf(c0, c1) |
        ((unsigned long long)pack2bf(c2, c3) << 32);
    __builtin_nontemporal_store(pk, xrow);
}

// ---------------------------------------------------------------------------
extern "C" void kernel_launch(void* const* d_in, const int* in_sizes, int n_in,
                              void* d_out, int out_size, void* d_ws,
                              size_t ws_size, hipStream_t stream) {
    const float* node_states = (const float*)d_in[0];
    const int* edges = (const int*)d_in[1];
    const float* ew = (const float*)d_in[2];
    const float* Wp = (const float*)d_in[4];
    const float* bp = (const float*)d_in[5];
    const float* Wk = (const float*)d_in[6];
    const float* Wa = (const float*)d_in[7];
    const float* Wo = (const float*)d_in[8];
    const float* bo = (const float*)d_in[9];
    float* out = (float*)d_out;

    char* ws = (char*)d_ws;
    __hip_bfloat16* xb16 = (__hip_bfloat16*)ws; ws += (size_t)M_PAD * 256 * 2;     // 25.6 MB
    __hip_bfloat16* xt16 = (__hip_bfloat16*)ws; ws += (size_t)M_PAD * 256 * 2;     // 25.6 MB
    unsigned int* xt8 = (unsigned int*)ws;      ws += (size_t)M_PAD * 256;         // 12.8 MB
    int2* edata = (int2*)ws;                    ws += (size_t)NE * 8;              // 8 MB
    float* a_src = (float*)ws;                  ws += (size_t)M_PAD * N_HEADS * 4;
    float* a_dst = (float*)ws;                  ws += (size_t)M_PAD * N_HEADS * 4;
    __hip_bfloat16* wpT = (__hip_bfloat16*)ws;  ws += 65536 * 2;
    __hip_bfloat16* wkT = (__hip_bfloat16*)ws;  ws += 131072 * 2;
    __hip_bfloat16* woT = (__hip_bfloat16*)ws;  ws += 16384 * 2;
    int* row_st = (int*)ws;

    prep_kernel<<<17435, 256, 0, stream>>>(node_states, edges, ew, Wp, Wk, Wo,
                                           xt16, edata, wpT, wkT, woT, row_st);

    // xb16 = relu(ns @ Wp + bp)  (bf16 residual master)
    gemm_mfma<true, false, false><<<dim3((N_NODES + 127) / 128, 2), 256, 0,
                                    stream>>>(xt16, wpT, bp, xb16, nullptr,
                                              nullptr, nullptr);

    // layer 0: GEMM -> xt8 (fp8) + fused alpha from fp32 accumulators
    gemm_mfma<false, true, true><<<dim3((N_NODES + 127) / 128, 2), 256, 0,
                                   stream>>>(xb16, wkT, nullptr, xt8, Wa,
                                             a_src, a_dst);
    edge_kernel<<<N_NODES / 4, 256, 0, stream>>>(
        (const unsigned long long*)edata, row_st, xt8, a_src, a_dst, xb16);

    // layer 1
    gemm_mfma<false, true, true><<<dim3((N_NODES + 127) / 128, 2), 256, 0,
                                   stream>>>(xb16, wkT + 65536, nullptr, xt8,
                                             Wa + 512, a_src, a_dst);
    edge_kernel<<<N_NODES / 4, 256, 0, stream>>>(
        (const unsigned long long*)edata, row_st, xt8, a_src, a_dst, xb16);

    // out = xb16 @ Wo + bo (bf16 MFMA, fp32 store)
    gemm_mfma_out<<<(N_NODES + 127) / 128, 256, 0, stream>>>(xb16, woT, bo, out);
}

// Round 13
// 288.025 us; speedup vs baseline: 1.0543x; 1.0543x over previous
//
#include <hip/hip_runtime.h>
#include <hip/hip_bf16.h>
#include <math.h>

#define N_NODES 50000
#define F_DIM 256
#define NE 1000000
#define N_HEADS 8
#define M_PAD 50048   // 128-row padded

typedef __attribute__((ext_vector_type(8))) short short8;   // 8 bf16 = 4 VGPRs
typedef __attribute__((ext_vector_type(4))) float floatx4;
typedef __attribute__((ext_vector_type(2))) float floatx2;
typedef __attribute__((ext_vector_type(4))) unsigned int uintx4;

__device__ __forceinline__ void load16_lds(const void* g, void* l) {
    __builtin_amdgcn_global_load_lds(
        (const __attribute__((address_space(1))) unsigned int*)(unsigned long long)g,
        (__attribute__((address_space(3))) unsigned int*)(unsigned int)(unsigned long long)l,
        16, 0, 0);
}

__device__ __forceinline__ unsigned int pack2bf(float a, float b) {
    __hip_bfloat16 t0 = __float2bfloat16(a), t1 = __float2bfloat16(b);
    unsigned short u0, u1;
    __builtin_memcpy(&u0, &t0, 2);
    __builtin_memcpy(&u1, &t1, 2);
    return (unsigned int)u0 | ((unsigned int)u1 << 16);
}

__device__ __forceinline__ float bf_lo(unsigned int u) {
    return __uint_as_float(u << 16);
}
__device__ __forceinline__ float bf_hi(unsigned int u) {
    return __uint_as_float(u & 0xffff0000u);
}

// pack 4 fp32 -> 4 fp8 e4m3 (bytes 0..3), HW packed converters
__device__ __forceinline__ unsigned int pack4fp8(float x, float y, float z,
                                                 float w) {
    int v = __builtin_amdgcn_cvt_pk_fp8_f32(x, y, 0, false);   // bytes 0,1
    v = __builtin_amdgcn_cvt_pk_fp8_f32(z, w, v, true);        // bytes 2,3
    return (unsigned int)v;
}

// ---------------------------------------------------------------------------
// merged prep: blocks [0,12500) conv_x; [12500,16407) edata pack;
// [16407,17239) weight transpose+bf16; [17239,17435) row_start.
// ---------------------------------------------------------------------------
__global__ __launch_bounds__(256) void prep_kernel(
    const float* __restrict__ node_states, const int* __restrict__ edges,
    const float* __restrict__ ew, const float* __restrict__ Wp,
    const float* __restrict__ Wk, const float* __restrict__ Wo,
    __hip_bfloat16* __restrict__ xt16, int2* __restrict__ edata,
    __hip_bfloat16* __restrict__ wpT, __hip_bfloat16* __restrict__ wkT,
    __hip_bfloat16* __restrict__ woT, int* __restrict__ row_start) {
    const int b = blockIdx.x;
    const int tid = threadIdx.x;
    if (b < 12500) {                       // node_states -> bf16
        const size_t i = ((size_t)b * 256 + tid) * 4;
        const float4 v = *(const float4*)(node_states + i);
        uint2 pk;
        pk.x = pack2bf(v.x, v.y);
        pk.y = pack2bf(v.z, v.w);
        *(uint2*)((unsigned short*)xt16 + i) = pk;
    } else if (b < 16407) {                // {dst, ew} pack
        const int e = (b - 12500) * 256 + tid;
        if (e < NE) {
            int2 d;
            d.x = edges[2 * e + 1];
            d.y = __float_as_int(ew[e]);
            edata[e] = d;
        }
    } else if (b < 17239) {                // weights -> BT bf16
        const int wb = b - 16407;
        if (wb < 256) {
            int idx = wb * 256 + tid;          // 65536 = [n][k]
            int n = idx >> 8, k = idx & 255;
            wpT[idx] = __float2bfloat16(Wp[k * 256 + n]);
        } else if (wb < 768) {
            int idx = (wb - 256) * 256 + tid;  // 131072 = [l][n][k]
            int l = idx >> 16, n = (idx >> 8) & 255, k = idx & 255;
            int h = n >> 5, u = n & 31;
            wkT[idx] = __float2bfloat16(Wk[(((l * 8 + h) * 256) + k) * 32 + u]);
        } else {
            int idx = (wb - 768) * 256 + tid;  // 16384 = [n(64)][k(256)]
            int n = idx >> 8, k = idx & 255;
            woT[idx] = __float2bfloat16(Wo[k * 64 + n]);
        }
    } else {                               // row_start = lower_bound(src, i)
        const int i = (b - 17239) * 256 + tid;
        if (i > N_NODES) return;
        if (i == N_NODES) { row_start[N_NODES] = NE; return; }
        int lo = 0, hi = NE;
        while (lo < hi) {
            int mid = (lo + hi) >> 1;
            if (edges[2 * mid] < i) lo = mid + 1; else hi = mid;
        }
        row_start[i] = lo;
    }
}

// ---------------------------------------------------------------------------
// MFMA GEMM: Y[M x 256] = A16[M x 256] @ B (BT as [256 n][256 k] bf16)
// 128x128 tile, 4 waves (2x2), 16x16x32 bf16 MFMA, operands swapped so lane
// holds C[m = lane&15 + 16mt][n0 + (lane>>4)*4 + 16nt .. +3].
// FP8OUT: Y is fp8 e4m3 (xt8), stores coalesced via LDS transpose.
// ALPHA: emit a_src/a_dst from the fp32 accumulators.
// ---------------------------------------------------------------------------
template <bool BIAS_RELU, bool FP8OUT, bool ALPHA>
__global__ __launch_bounds__(256) void gemm_mfma(
    const __hip_bfloat16* __restrict__ A16, const __hip_bfloat16* __restrict__ BT,
    const float* __restrict__ bias, void* __restrict__ Y,
    const float* __restrict__ Wa_l, float* __restrict__ a_srcO,
    float* __restrict__ a_dstO) {
    __shared__ __align__(16) short lA[128 * 32];
    __shared__ __align__(16) short lB[128 * 32];
    const int tid = threadIdx.x;
    const int row0 = blockIdx.x * 128;
    const int n0 = blockIdx.y * 128;
    const int w = tid >> 6, l = tid & 63;
    const int wr = w >> 1, wc = w & 1;

    const __hip_bfloat16* gA = A16 + (size_t)(row0 + (tid >> 2)) * 256 + (tid & 3) * 8;
    const __hip_bfloat16* gB = BT + (size_t)(n0 + (tid >> 2)) * 256 + (tid & 3) * 8;
    short* dA = lA + tid * 8;
    short* dB = lB + tid * 8;

    floatx4 acc[4][4] = {};

    const short* pa = lA + (wr * 64 + (l & 15)) * 32 + (l >> 4) * 8;
    const short* pb = lB + (wc * 64 + (l & 15)) * 32 + (l >> 4) * 8;

    for (int kk = 0; kk < 8; ++kk) {
        const int ko = kk * 32;
        load16_lds(gA + ko, dA);
        load16_lds(gA + 64 * 256 + ko, dA + 256 * 8);
        load16_lds(gB + ko, dB);
        load16_lds(gB + 64 * 256 + ko, dB + 256 * 8);
        __syncthreads();
        short8 af[4], bf[4];
#pragma unroll
        for (int t = 0; t < 4; ++t) {
            af[t] = *(const short8*)(pa + t * 16 * 32);
            bf[t] = *(const short8*)(pb + t * 16 * 32);
        }
#pragma unroll
        for (int mt = 0; mt < 4; ++mt)
#pragma unroll
            for (int nt = 0; nt < 4; ++nt)
                acc[mt][nt] = __builtin_amdgcn_mfma_f32_16x16x32_bf16(
                    bf[nt], af[mt], acc[mt][nt], 0, 0, 0);
        __syncthreads();
    }

    const int m_base = row0 + wr * 64 + (l & 15);
    const int n_base = n0 + wc * 64 + ((l >> 4) << 2);

    if constexpr (ALPHA) {
        const int lg = l >> 4;
        float4 wS[2][2], wD[2][2];
#pragma unroll
        for (int hl = 0; hl < 2; ++hl) {
            const int h = (n0 >> 5) + wc * 2 + hl;
#pragma unroll
            for (int p = 0; p < 2; ++p) {
                wS[hl][p] = *(const float4*)(Wa_l + h * 64 + p * 16 + lg * 4);
                wD[hl][p] =
                    *(const float4*)(Wa_l + h * 64 + 32 + p * 16 + lg * 4);
            }
        }
        float aS[4][2], aD[4][2];
#pragma unroll
        for (int mt = 0; mt < 4; ++mt)
#pragma unroll
            for (int hl = 0; hl < 2; ++hl) {
                float s = 0.f, d = 0.f;
#pragma unroll
                for (int p = 0; p < 2; ++p) {
                    const floatx4 v = acc[mt][2 * hl + p];
                    const float4 ws = wS[hl][p], wd = wD[hl][p];
                    s += v.x * ws.x + v.y * ws.y + v.z * ws.z + v.w * ws.w;
                    d += v.x * wd.x + v.y * wd.y + v.z * wd.z + v.w * wd.w;
                }
                s += __shfl_xor(s, 16);
                s += __shfl_xor(s, 32);
                d += __shfl_xor(d, 16);
                d += __shfl_xor(d, 32);
                aS[mt][hl] = s;
                aD[mt][hl] = d;
            }
        if (lg == 0) {   // lanes 0..15: one writer per (m, h)
#pragma unroll
            for (int mt = 0; mt < 4; ++mt) {
                const int m = m_base + mt * 16;   // < M_PAD (buffers padded)
#pragma unroll
                for (int hl = 0; hl < 2; ++hl) {
                    const int h = (n0 >> 5) + wc * 2 + hl;
                    a_srcO[(size_t)m * 8 + h] = aS[mt][hl];
                    a_dstO[(size_t)m * 8 + h] = aD[mt][hl];
                }
            }
        }
    }

    if constexpr (FP8OUT) {
        // pack fp8 in-register, then LDS transpose -> coalesced dwordx4 rows
        unsigned int p8[4][4];
#pragma unroll
        for (int mt = 0; mt < 4; ++mt)
#pragma unroll
            for (int nt = 0; nt < 4; ++nt) {
                const floatx4 v = acc[mt][nt];
                p8[mt][nt] = pack4fp8(v.x, v.y, v.z, v.w);
            }
        unsigned int* lds32 = (unsigned int*)lA;   // 32 rows x 33 dwords (pad)
        const int row_local = wr * 16 + (l & 15);  // 0..31
        const int colb = wc * 16 + (l >> 4);       // dword col, +nt*4
        const int band = tid >> 7;                 // 0..1 (row half)
        const int rr = (tid >> 3) & 15;            // row within band
        const int dq = (tid & 7) << 2;             // dword col 0,4,..,28
        unsigned int* gout = (unsigned int*)Y +
                             (size_t)(row0 + band * 64) * 64 + (n0 >> 2) + dq;
#pragma unroll
        for (int mt = 0; mt < 4; ++mt) {
            __syncthreads();
#pragma unroll
            for (int nt = 0; nt < 4; ++nt)
                lds32[row_local * 33 + colb + nt * 4] = p8[mt][nt];
            __syncthreads();
            const unsigned int* src = lds32 + (band * 16 + rr) * 33 + dq;
            uintx4 o;
            o.x = src[0]; o.y = src[1]; o.z = src[2]; o.w = src[3];
            *(uintx4*)(gout + (size_t)(mt * 16 + rr) * 64) = o;
        }
    } else {
#pragma unroll
        for (int mt = 0; mt < 4; ++mt) {
            const int m = m_base + mt * 16;
            if (m >= N_NODES) continue;
#pragma unroll
            for (int nt = 0; nt < 4; ++nt) {
                const int n = n_base + nt * 16;
                floatx4 v = acc[mt][nt];
                if (BIAS_RELU) {
                    const float4 bb = *(const float4*)(bias + n);
                    v.x = fmaxf(v.x + bb.x, 0.f);
                    v.y = fmaxf(v.y + bb.y, 0.f);
                    v.z = fmaxf(v.z + bb.z, 0.f);
                    v.w = fmaxf(v.w + bb.w, 0.f);
                }
                uint2 pk;
                pk.x = pack2bf(v.x, v.y);
                pk.y = pack2bf(v.z, v.w);
                *(uint2*)((unsigned short*)Y + ((size_t)m << 8) + n) = pk;
            }
        }
    }
}

// ---------------------------------------------------------------------------
// Final projection: out[M x 64] = xb16[M x 256] @ Wo + bo  (fp32 out)
// ---------------------------------------------------------------------------
__global__ __launch_bounds__(256) void gemm_mfma_out(
    const __hip_bfloat16* __restrict__ A16, const __hip_bfloat16* __restrict__ BT,
    const float* __restrict__ bias, float* __restrict__ out) {
    __shared__ __align__(16) short lA[128 * 32];
    __shared__ __align__(16) short lB[64 * 32];
    const int tid = threadIdx.x;
    const int row0 = blockIdx.x * 128;
    const int w = tid >> 6, l = tid & 63;

    const __hip_bfloat16* gA = A16 + (size_t)(row0 + (tid >> 2)) * 256 + (tid & 3) * 8;
    const __hip_bfloat16* gB = BT + (size_t)(tid >> 2) * 256 + (tid & 3) * 8;
    short* dA = lA + tid * 8;
    short* dB = lB + tid * 8;   // 256 threads * 8 shorts = exactly 64*32

    floatx4 acc[2][4] = {};

    const short* pa = lA + (w * 32 + (l & 15)) * 32 + (l >> 4) * 8;
    const short* pb = lB + (l & 15) * 32 + (l >> 4) * 8;

    for (int kk = 0; kk < 8; ++kk) {
        const int ko = kk * 32;
        load16_lds(gA + ko, dA);
        load16_lds(gA + 64 * 256 + ko, dA + 256 * 8);
        load16_lds(gB + ko, dB);
        __syncthreads();
        short8 af[2], bf[4];
#pragma unroll
        for (int t = 0; t < 2; ++t) af[t] = *(const short8*)(pa + t * 16 * 32);
#pragma unroll
        for (int t = 0; t < 4; ++t) bf[t] = *(const short8*)(pb + t * 16 * 32);
#pragma unroll
        for (int mt = 0; mt < 2; ++mt)
#pragma unroll
            for (int nt = 0; nt < 4; ++nt)
                acc[mt][nt] = __builtin_amdgcn_mfma_f32_16x16x32_bf16(
                    bf[nt], af[mt], acc[mt][nt], 0, 0, 0);
        __syncthreads();
    }

    const int m_base = row0 + w * 32 + (l & 15);
    const int n_base = (l >> 4) << 2;
#pragma unroll
    for (int mt = 0; mt < 2; ++mt) {
        const int m = m_base + mt * 16;
        if (m >= N_NODES) continue;
#pragma unroll
        for (int nt = 0; nt < 4; ++nt) {
            const int n = n_base + nt * 16;
            const float4 bb = *(const float4*)(bias + n);
            floatx4 v = acc[mt][nt];
            float4 o = {v.x + bb.x, v.y + bb.y, v.z + bb.z, v.w + bb.w};
            *(float4*)(&out[(size_t)m * 64 + n]) = o;
        }
    }
}

// ---------------------------------------------------------------------------
// fused score + aggregation (R11 proven shape + 32-bit addressing):
// 1 wave per node (wave-uniform edge walk -> scalar bases), lane = 4 fp8
// features, 4-edge unroll. bf16 residual master xb16; streaming NT.
// ---------------------------------------------------------------------------
__device__ __forceinline__ float edge_score(float asrc, float ad, float w) {
    float sp = (asrc + ad) * w;
    sp = fmaxf(sp, 0.2f * sp);            // leaky_relu(0.2), branchless
    sp = fminf(fmaxf(sp, -2.f), 2.f);     // clip
    return __expf(sp);
}

#define ACC8(u, s)                                               \
    {                                                            \
        const floatx2 f01 = __builtin_amdgcn_cvt_pk_f32_fp8(u, false); \
        const floatx2 f23 = __builtin_amdgcn_cvt_pk_f32_fp8(u, true);  \
        a0 = fmaf(f01.x, s, a0);                                 \
        a1 = fmaf(f01.y, s, a1);                                 \
        a2 = fmaf(f23.x, s, a2);                                 \
        a3 = fmaf(f23.y, s, a3);                                 \
    }

__global__ __launch_bounds__(256) void edge_kernel(
    const unsigned long long* __restrict__ edata,
    const int* __restrict__ row_start, const unsigned int* __restrict__ xt8,
    const float* __restrict__ a_src, const float* __restrict__ a_dst,
    __hip_bfloat16* __restrict__ xb16) {
    const int tid = threadIdx.x;
    const int node =
        __builtin_amdgcn_readfirstlane(blockIdx.x * 4 + (tid >> 6));
    const unsigned l = (unsigned)(tid & 63);
    const unsigned h = l >> 3;
    const float asrc = a_src[(unsigned)node * 8u + h];
    const int e0 = __builtin_amdgcn_readfirstlane(row_start[node]);
    const int e1 = __builtin_amdgcn_readfirstlane(row_start[node + 1]);

    // residual row (bf16), non-temporal: streamed once per node
    unsigned long long* xrow =
        (unsigned long long*)((unsigned short*)xb16 + (size_t)node * 256 +
                              l * 4);
    const unsigned long long xin = __builtin_nontemporal_load(xrow);

    float a0 = 0.f, a1 = 0.f, a2 = 0.f, a3 = 0.f, ssum = 0.f;
    int e = e0;
    for (; e + 4 <= e1; e += 4) {
        const unsigned long long ed0 = __builtin_nontemporal_load(edata + e);
        const unsigned long long ed1 = __builtin_nontemporal_load(edata + e + 1);
        const unsigned long long ed2 = __builtin_nontemporal_load(edata + e + 2);
        const unsigned long long ed3 = __builtin_nontemporal_load(edata + e + 3);
        const unsigned d0 = (unsigned int)ed0;
        const unsigned d1 = (unsigned int)ed1;
        const unsigned d2 = (unsigned int)ed2;
        const unsigned d3 = (unsigned int)ed3;
        const float w0 = __uint_as_float((unsigned int)(ed0 >> 32));
        const float w1 = __uint_as_float((unsigned int)(ed1 >> 32));
        const float w2 = __uint_as_float((unsigned int)(ed2 >> 32));
        const float w3 = __uint_as_float((unsigned int)(ed3 >> 32));
        const float s0 = edge_score(asrc, a_dst[d0 * 8u + h], w0);
        const float s1 = edge_score(asrc, a_dst[d1 * 8u + h], w1);
        const float s2 = edge_score(asrc, a_dst[d2 * 8u + h], w2);
        const float s3 = edge_score(asrc, a_dst[d3 * 8u + h], w3);
        const unsigned int u0 = xt8[d0 * 64u + l];
        const unsigned int u1 = xt8[d1 * 64u + l];
        const unsigned int u2 = xt8[d2 * 64u + l];
        const unsigned int u3 = xt8[d3 * 64u + l];
        ACC8(u0, s0);
        ACC8(u1, s1);
        ACC8(u2, s2);
        ACC8(u3, s3);
        ssum += (s0 + s1) + (s2 + s3);
    }
    for (; e < e1; ++e) {
        const unsigned long long ed = __builtin_nontemporal_load(edata + e);
        const unsigned d = (unsigned int)ed;
        const float w = __uint_as_float((unsigned int)(ed >> 32));
        const float s = edge_score(asrc, a_dst[d * 8u + h], w);
        const unsigned int u = xt8[d * 64u + l];
        ACC8(u, s);
        ssum += s;
    }
    const float inv = (e1 > e0) ? 1.f / ssum : 0.f;
    // residual add in fp32, round once to bf16
    const unsigned int xlo = (unsigned int)xin;
    const unsigned int xhi = (unsigned int)(xin >> 32);
    const float c0 = bf_lo(xlo) + fmaxf(a0 * inv, 0.f);
    const float c1 = bf_hi(xlo) + fmaxf(a1 * inv, 0.f);
    const float c2 = bf_lo(xhi) + fmaxf(a2 * inv, 0.f);
    const float c3 = bf_hi(xhi) + fmaxf(a3 * inv, 0.f);
    const unsigned long long pk =
        (unsigned long long)pack2bf(c0, c1) |
        ((unsigned long long)pack2bf(c2, c3) << 32);
    __builtin_nontemporal_store(pk, xrow);
}

// ---------------------------------------------------------------------------
extern "C" void kernel_launch(void* const* d_in, const int* in_sizes, int n_in,
                              void* d_out, int out_size, void* d_ws,
                              size_t ws_size, hipStream_t stream) {
    const float* node_states = (const float*)d_in[0];
    const int* edges = (const int*)d_in[1];
    const float* ew = (const float*)d_in[2];
    const float* Wp = (const float*)d_in[4];
    const float* bp = (const float*)d_in[5];
    const float* Wk = (const float*)d_in[6];
    const float* Wa = (const float*)d_in[7];
    const float* Wo = (const float*)d_in[8];
    const float* bo = (const float*)d_in[9];
    float* out = (float*)d_out;

    char* ws = (char*)d_ws;
    __hip_bfloat16* xb16 = (__hip_bfloat16*)ws; ws += (size_t)M_PAD * 256 * 2;     // 25.6 MB
    __hip_bfloat16* xt16 = (__hip_bfloat16*)ws; ws += (size_t)M_PAD * 256 * 2;     // 25.6 MB
    unsigned int* xt8 = (unsigned int*)ws;      ws += (size_t)M_PAD * 256;         // 12.8 MB
    int2* edata = (int2*)ws;                    ws += (size_t)NE * 8;              // 8 MB
    float* a_src = (float*)ws;                  ws += (size_t)M_PAD * N_HEADS * 4;
    float* a_dst = (float*)ws;                  ws += (size_t)M_PAD * N_HEADS * 4;
    __hip_bfloat16* wpT = (__hip_bfloat16*)ws;  ws += 65536 * 2;
    __hip_bfloat16* wkT = (__hip_bfloat16*)ws;  ws += 131072 * 2;
    __hip_bfloat16* woT = (__hip_bfloat16*)ws;  ws += 16384 * 2;
    int* row_st = (int*)ws;

    prep_kernel<<<17435, 256, 0, stream>>>(node_states, edges, ew, Wp, Wk, Wo,
                                           xt16, edata, wpT, wkT, woT, row_st);

    // xb16 = relu(ns @ Wp + bp)  (bf16 residual master)
    gemm_mfma<true, false, false><<<dim3((N_NODES + 127) / 128, 2), 256, 0,
                                    stream>>>(xt16, wpT, bp, xb16, nullptr,
                                              nullptr, nullptr);

    // layer 0: GEMM -> xt8 (fp8, coalesced stores) + fused alpha
    gemm_mfma<false, true, true><<<dim3((N_NODES + 127) / 128, 2), 256, 0,
                                   stream>>>(xb16, wkT, nullptr, xt8, Wa,
                                             a_src, a_dst);
    edge_kernel<<<N_NODES / 4, 256, 0, stream>>>(
        (const unsigned long long*)edata, row_st, xt8, a_src, a_dst, xb16);

    // layer 1
    gemm_mfma<false, true, true><<<dim3((N_NODES + 127) / 128, 2), 256, 0,
                                   stream>>>(xb16, wkT + 65536, nullptr, xt8,
                                             Wa + 512, a_src, a_dst);
    edge_kernel<<<N_NODES / 4, 256, 0, stream>>>(
        (const unsigned long long*)edata, row_st, xt8, a_src, a_dst, xb16);

    // out = xb16 @ Wo + bo (bf16 MFMA, fp32 store)
    gemm_mfma_out<<<(N_NODES + 127) / 128, 256, 0, stream>>>(xb16, woT, bo, out);
}

// Round 14
// 282.849 us; speedup vs baseline: 1.0736x; 1.0183x over previous
//
#include <hip/hip_runtime.h>
#include <hip/hip_bf16.h>
#include <math.h>

#define N_NODES 50000
#define F_DIM 256
#define NE 1000000
#define N_HEADS 8
#define M_PAD 50048   // 128-row padded

typedef __attribute__((ext_vector_type(8))) short short8;   // 8 bf16 = 4 VGPRs
typedef __attribute__((ext_vector_type(4))) float floatx4;
typedef __attribute__((ext_vector_type(2))) float floatx2;
typedef __attribute__((ext_vector_type(4))) unsigned int uintx4;

__device__ __forceinline__ void load16_lds(const void* g, void* l) {
    __builtin_amdgcn_global_load_lds(
        (const __attribute__((address_space(1))) unsigned int*)(unsigned long long)g,
        (__attribute__((address_space(3))) unsigned int*)(unsigned int)(unsigned long long)l,
        16, 0, 0);
}

__device__ __forceinline__ unsigned int pack2bf(float a, float b) {
    __hip_bfloat16 t0 = __float2bfloat16(a), t1 = __float2bfloat16(b);
    unsigned short u0, u1;
    __builtin_memcpy(&u0, &t0, 2);
    __builtin_memcpy(&u1, &t1, 2);
    return (unsigned int)u0 | ((unsigned int)u1 << 16);
}

__device__ __forceinline__ float bf_lo(unsigned int u) {
    return __uint_as_float(u << 16);
}
__device__ __forceinline__ float bf_hi(unsigned int u) {
    return __uint_as_float(u & 0xffff0000u);
}

// pack 4 fp32 -> 4 fp8 e4m3 (bytes 0..3), HW packed converters
__device__ __forceinline__ unsigned int pack4fp8(float x, float y, float z,
                                                 float w) {
    int v = __builtin_amdgcn_cvt_pk_fp8_f32(x, y, 0, false);   // bytes 0,1
    v = __builtin_amdgcn_cvt_pk_fp8_f32(z, w, v, true);        // bytes 2,3
    return (unsigned int)v;
}

// ---------------------------------------------------------------------------
// merged prep: blocks [0,12500) conv_x; [12500,16407) edata pack;
// [16407,17239) weight transpose+bf16; [17239,17435) row_start.
// ---------------------------------------------------------------------------
__global__ __launch_bounds__(256) void prep_kernel(
    const float* __restrict__ node_states, const int* __restrict__ edges,
    const float* __restrict__ ew, const float* __restrict__ Wp,
    const float* __restrict__ Wk, const float* __restrict__ Wo,
    __hip_bfloat16* __restrict__ xt16, int2* __restrict__ edata,
    __hip_bfloat16* __restrict__ wpT, __hip_bfloat16* __restrict__ wkT,
    __hip_bfloat16* __restrict__ woT, int* __restrict__ row_start) {
    const int b = blockIdx.x;
    const int tid = threadIdx.x;
    if (b < 12500) {                       // node_states -> bf16
        const size_t i = ((size_t)b * 256 + tid) * 4;
        const float4 v = *(const float4*)(node_states + i);
        uint2 pk;
        pk.x = pack2bf(v.x, v.y);
        pk.y = pack2bf(v.z, v.w);
        *(uint2*)((unsigned short*)xt16 + i) = pk;
    } else if (b < 16407) {                // {dst, ew} pack
        const int e = (b - 12500) * 256 + tid;
        if (e < NE) {
            int2 d;
            d.x = edges[2 * e + 1];
            d.y = __float_as_int(ew[e]);
            edata[e] = d;
        }
    } else if (b < 17239) {                // weights -> BT bf16
        const int wb = b - 16407;
        if (wb < 256) {
            int idx = wb * 256 + tid;          // 65536 = [n][k]
            int n = idx >> 8, k = idx & 255;
            wpT[idx] = __float2bfloat16(Wp[k * 256 + n]);
        } else if (wb < 768) {
            int idx = (wb - 256) * 256 + tid;  // 131072 = [l][n][k]
            int l = idx >> 16, n = (idx >> 8) & 255, k = idx & 255;
            int h = n >> 5, u = n & 31;
            wkT[idx] = __float2bfloat16(Wk[(((l * 8 + h) * 256) + k) * 32 + u]);
        } else {
            int idx = (wb - 768) * 256 + tid;  // 16384 = [n(64)][k(256)]
            int n = idx >> 8, k = idx & 255;
            woT[idx] = __float2bfloat16(Wo[k * 64 + n]);
        }
    } else {                               // row_start = lower_bound(src, i)
        const int i = (b - 17239) * 256 + tid;
        if (i > N_NODES) return;
        if (i == N_NODES) { row_start[N_NODES] = NE; return; }
        int lo = 0, hi = NE;
        while (lo < hi) {
            int mid = (lo + hi) >> 1;
            if (edges[2 * mid] < i) lo = mid + 1; else hi = mid;
        }
        row_start[i] = lo;
    }
}

// ---------------------------------------------------------------------------
// MFMA GEMM: Y[M x 256] = A16[M x 256] @ B (BT as [256 n][256 k] bf16)
// 128x128 tile, 4 waves (2x2), 16x16x32 bf16 MFMA.
// K-loop: BK=64 as TWO 128x32 planes per tile (each plane = the proven
// BK=32 layout; global_load_lds needs lane-contiguous dest, so planes keep
// the staging map and LDS bank behavior identical) -> 8 barriers not 16.
// FP8OUT: Y is fp8 e4m3 (xt8), stores coalesced via LDS transpose.
// ALPHA: emit a_src/a_dst from the fp32 accumulators.
// ---------------------------------------------------------------------------
template <bool BIAS_RELU, bool FP8OUT, bool ALPHA>
__global__ __launch_bounds__(256) void gemm_mfma(
    const __hip_bfloat16* __restrict__ A16, const __hip_bfloat16* __restrict__ BT,
    const float* __restrict__ bias, void* __restrict__ Y,
    const float* __restrict__ Wa_l, float* __restrict__ a_srcO,
    float* __restrict__ a_dstO) {
    __shared__ __align__(16) short lA[128 * 64];   // 2 planes of 128x32
    __shared__ __align__(16) short lB[128 * 64];
    const int tid = threadIdx.x;
    const int row0 = blockIdx.x * 128;
    const int n0 = blockIdx.y * 128;
    const int w = tid >> 6, l = tid & 63;
    const int wr = w >> 1, wc = w & 1;

    const __hip_bfloat16* gA = A16 + (size_t)(row0 + (tid >> 2)) * 256 + (tid & 3) * 8;
    const __hip_bfloat16* gB = BT + (size_t)(n0 + (tid >> 2)) * 256 + (tid & 3) * 8;
    short* dA = lA + tid * 8;
    short* dB = lB + tid * 8;

    floatx4 acc[4][4] = {};

    for (int kk = 0; kk < 4; ++kk) {
        const int ko = kk * 64;
#pragma unroll
        for (int p = 0; p < 2; ++p) {   // K-plane p covers cols ko+32p..+31
            load16_lds(gA + ko + p * 32, dA + p * 4096);
            load16_lds(gA + 64 * 256 + ko + p * 32, dA + p * 4096 + 2048);
            load16_lds(gB + ko + p * 32, dB + p * 4096);
            load16_lds(gB + 64 * 256 + ko + p * 32, dB + p * 4096 + 2048);
        }
        __syncthreads();
#pragma unroll
        for (int kh = 0; kh < 2; ++kh) {
            const short* pa =
                lA + kh * 4096 + (wr * 64 + (l & 15)) * 32 + (l >> 4) * 8;
            const short* pb =
                lB + kh * 4096 + (wc * 64 + (l & 15)) * 32 + (l >> 4) * 8;
            short8 af[4], bf[4];
#pragma unroll
            for (int t = 0; t < 4; ++t) {
                af[t] = *(const short8*)(pa + t * 16 * 32);
                bf[t] = *(const short8*)(pb + t * 16 * 32);
            }
#pragma unroll
            for (int mt = 0; mt < 4; ++mt)
#pragma unroll
                for (int nt = 0; nt < 4; ++nt)
                    acc[mt][nt] = __builtin_amdgcn_mfma_f32_16x16x32_bf16(
                        bf[nt], af[mt], acc[mt][nt], 0, 0, 0);
        }
        __syncthreads();
    }

    const int m_base = row0 + wr * 64 + (l & 15);
    const int n_base = n0 + wc * 64 + ((l >> 4) << 2);

    if constexpr (ALPHA) {
        const int lg = l >> 4;
        float4 wS[2][2], wD[2][2];
#pragma unroll
        for (int hl = 0; hl < 2; ++hl) {
            const int h = (n0 >> 5) + wc * 2 + hl;
#pragma unroll
            for (int p = 0; p < 2; ++p) {
                wS[hl][p] = *(const float4*)(Wa_l + h * 64 + p * 16 + lg * 4);
                wD[hl][p] =
                    *(const float4*)(Wa_l + h * 64 + 32 + p * 16 + lg * 4);
            }
        }
        float aS[4][2], aD[4][2];
#pragma unroll
        for (int mt = 0; mt < 4; ++mt)
#pragma unroll
            for (int hl = 0; hl < 2; ++hl) {
                float s = 0.f, d = 0.f;
#pragma unroll
                for (int p = 0; p < 2; ++p) {
                    const floatx4 v = acc[mt][2 * hl + p];
                    const float4 ws = wS[hl][p], wd = wD[hl][p];
                    s += v.x * ws.x + v.y * ws.y + v.z * ws.z + v.w * ws.w;
                    d += v.x * wd.x + v.y * wd.y + v.z * wd.z + v.w * wd.w;
                }
                s += __shfl_xor(s, 16);
                s += __shfl_xor(s, 32);
                d += __shfl_xor(d, 16);
                d += __shfl_xor(d, 32);
                aS[mt][hl] = s;
                aD[mt][hl] = d;
            }
        if (lg == 0) {   // lanes 0..15: one writer per (m, h)
#pragma unroll
            for (int mt = 0; mt < 4; ++mt) {
                const int m = m_base + mt * 16;   // < M_PAD (buffers padded)
#pragma unroll
                for (int hl = 0; hl < 2; ++hl) {
                    const int h = (n0 >> 5) + wc * 2 + hl;
                    a_srcO[(size_t)m * 8 + h] = aS[mt][hl];
                    a_dstO[(size_t)m * 8 + h] = aD[mt][hl];
                }
            }
        }
    }

    if constexpr (FP8OUT) {
        // pack fp8 in-register, then LDS transpose -> coalesced dwordx4 rows
        unsigned int p8[4][4];
#pragma unroll
        for (int mt = 0; mt < 4; ++mt)
#pragma unroll
            for (int nt = 0; nt < 4; ++nt) {
                const floatx4 v = acc[mt][nt];
                p8[mt][nt] = pack4fp8(v.x, v.y, v.z, v.w);
            }
        unsigned int* lds32 = (unsigned int*)lA;   // 32 rows x 33 dwords (pad)
        const int row_local = wr * 16 + (l & 15);  // 0..31
        const int colb = wc * 16 + (l >> 4);       // dword col, +nt*4
        const int band = tid >> 7;                 // 0..1 (row half)
        const int rr = (tid >> 3) & 15;            // row within band
        const int dq = (tid & 7) << 2;             // dword col 0,4,..,28
        unsigned int* gout = (unsigned int*)Y +
                             (size_t)(row0 + band * 64) * 64 + (n0 >> 2) + dq;
#pragma unroll
        for (int mt = 0; mt < 4; ++mt) {
            __syncthreads();
#pragma unroll
            for (int nt = 0; nt < 4; ++nt)
                lds32[row_local * 33 + colb + nt * 4] = p8[mt][nt];
            __syncthreads();
            const unsigned int* src = lds32 + (band * 16 + rr) * 33 + dq;
            uintx4 o;
            o.x = src[0]; o.y = src[1]; o.z = src[2]; o.w = src[3];
            *(uintx4*)(gout + (size_t)(mt * 16 + rr) * 64) = o;
        }
    } else {
#pragma unroll
        for (int mt = 0; mt < 4; ++mt) {
            const int m = m_base + mt * 16;
            if (m >= N_NODES) continue;
#pragma unroll
            for (int nt = 0; nt < 4; ++nt) {
                const int n = n_base + nt * 16;
                floatx4 v = acc[mt][nt];
                if (BIAS_RELU) {
                    const float4 bb = *(const float4*)(bias + n);
                    v.x = fmaxf(v.x + bb.x, 0.f);
                    v.y = fmaxf(v.y + bb.y, 0.f);
                    v.z = fmaxf(v.z + bb.z, 0.f);
                    v.w = fmaxf(v.w + bb.w, 0.f);
                }
                uint2 pk;
                pk.x = pack2bf(v.x, v.y);
                pk.y = pack2bf(v.z, v.w);
                *(uint2*)((unsigned short*)Y + ((size_t)m << 8) + n) = pk;
            }
        }
    }
}

// ---------------------------------------------------------------------------
// Final projection: out[M x 64] = xb16[M x 256] @ Wo + bo  (fp32 out)
// ---------------------------------------------------------------------------
__global__ __launch_bounds__(256) void gemm_mfma_out(
    const __hip_bfloat16* __restrict__ A16, const __hip_bfloat16* __restrict__ BT,
    const float* __restrict__ bias, float* __restrict__ out) {
    __shared__ __align__(16) short lA[128 * 32];
    __shared__ __align__(16) short lB[64 * 32];
    const int tid = threadIdx.x;
    const int row0 = blockIdx.x * 128;
    const int w = tid >> 6, l = tid & 63;

    const __hip_bfloat16* gA = A16 + (size_t)(row0 + (tid >> 2)) * 256 + (tid & 3) * 8;
    const __hip_bfloat16* gB = BT + (size_t)(tid >> 2) * 256 + (tid & 3) * 8;
    short* dA = lA + tid * 8;
    short* dB = lB + tid * 8;   // 256 threads * 8 shorts = exactly 64*32

    floatx4 acc[2][4] = {};

    const short* pa = lA + (w * 32 + (l & 15)) * 32 + (l >> 4) * 8;
    const short* pb = lB + (l & 15) * 32 + (l >> 4) * 8;

    for (int kk = 0; kk < 8; ++kk) {
        const int ko = kk * 32;
        load16_lds(gA + ko, dA);
        load16_lds(gA + 64 * 256 + ko, dA + 256 * 8);
        load16_lds(gB + ko, dB);
        __syncthreads();
        short8 af[2], bf[4];
#pragma unroll
        for (int t = 0; t < 2; ++t) af[t] = *(const short8*)(pa + t * 16 * 32);
#pragma unroll
        for (int t = 0; t < 4; ++t) bf[t] = *(const short8*)(pb + t * 16 * 32);
#pragma unroll
        for (int mt = 0; mt < 2; ++mt)
#pragma unroll
            for (int nt = 0; nt < 4; ++nt)
                acc[mt][nt] = __builtin_amdgcn_mfma_f32_16x16x32_bf16(
                    bf[nt], af[mt], acc[mt][nt], 0, 0, 0);
        __syncthreads();
    }

    const int m_base = row0 + w * 32 + (l & 15);
    const int n_base = (l >> 4) << 2;
#pragma unroll
    for (int mt = 0; mt < 2; ++mt) {
        const int m = m_base + mt * 16;
        if (m >= N_NODES) continue;
#pragma unroll
        for (int nt = 0; nt < 4; ++nt) {
            const int n = n_base + nt * 16;
            const float4 bb = *(const float4*)(bias + n);
            floatx4 v = acc[mt][nt];
            float4 o = {v.x + bb.x, v.y + bb.y, v.z + bb.z, v.w + bb.w};
            *(float4*)(&out[(size_t)m * 64 + n]) = o;
        }
    }
}

// ---------------------------------------------------------------------------
// fused score + aggregation (R11 proven shape + 32-bit addressing):
// 1 wave per node (wave-uniform edge walk -> scalar bases), lane = 4 fp8
// features, 4-edge unroll. bf16 residual master xb16; streaming NT.
// ---------------------------------------------------------------------------
__device__ __forceinline__ float edge_score(float asrc, float ad, float w) {
    float sp = (asrc + ad) * w;
    sp = fmaxf(sp, 0.2f * sp);            // leaky_relu(0.2), branchless
    sp = fminf(fmaxf(sp, -2.f), 2.f);     // clip
    return __expf(sp);
}

#define ACC8(u, s)                                               \
    {                                                            \
        const floatx2 f01 = __builtin_amdgcn_cvt_pk_f32_fp8(u, false); \
        const floatx2 f23 = __builtin_amdgcn_cvt_pk_f32_fp8(u, true);  \
        a0 = fmaf(f01.x, s, a0);                                 \
        a1 = fmaf(f01.y, s, a1);                                 \
        a2 = fmaf(f23.x, s, a2);                                 \
        a3 = fmaf(f23.y, s, a3);                                 \
    }

__global__ __launch_bounds__(256) void edge_kernel(
    const unsigned long long* __restrict__ edata,
    const int* __restrict__ row_start, const unsigned int* __restrict__ xt8,
    const float* __restrict__ a_src, const float* __restrict__ a_dst,
    __hip_bfloat16* __restrict__ xb16) {
    const int tid = threadIdx.x;
    const int node =
        __builtin_amdgcn_readfirstlane(blockIdx.x * 4 + (tid >> 6));
    const unsigned l = (unsigned)(tid & 63);
    const unsigned h = l >> 3;
    const float asrc = a_src[(unsigned)node * 8u + h];
    const int e0 = __builtin_amdgcn_readfirstlane(row_start[node]);
    const int e1 = __builtin_amdgcn_readfirstlane(row_start[node + 1]);

    // residual row (bf16), non-temporal: streamed once per node
    unsigned long long* xrow =
        (unsigned long long*)((unsigned short*)xb16 + (size_t)node * 256 +
                              l * 4);
    const unsigned long long xin = __builtin_nontemporal_load(xrow);

    float a0 = 0.f, a1 = 0.f, a2 = 0.f, a3 = 0.f, ssum = 0.f;
    int e = e0;
    for (; e + 4 <= e1; e += 4) {
        const unsigned long long ed0 = __builtin_nontemporal_load(edata + e);
        const unsigned long long ed1 = __builtin_nontemporal_load(edata + e + 1);
        const unsigned long long ed2 = __builtin_nontemporal_load(edata + e + 2);
        const unsigned long long ed3 = __builtin_nontemporal_load(edata + e + 3);
        const unsigned d0 = (unsigned int)ed0;
        const unsigned d1 = (unsigned int)ed1;
        const unsigned d2 = (unsigned int)ed2;
        const unsigned d3 = (unsigned int)ed3;
        const float w0 = __uint_as_float((unsigned int)(ed0 >> 32));
        const float w1 = __uint_as_float((unsigned int)(ed1 >> 32));
        const float w2 = __uint_as_float((unsigned int)(ed2 >> 32));
        const float w3 = __uint_as_float((unsigned int)(ed3 >> 32));
        const float s0 = edge_score(asrc, a_dst[d0 * 8u + h], w0);
        const float s1 = edge_score(asrc, a_dst[d1 * 8u + h], w1);
        const float s2 = edge_score(asrc, a_dst[d2 * 8u + h], w2);
        const float s3 = edge_score(asrc, a_dst[d3 * 8u + h], w3);
        const unsigned int u0 = xt8[d0 * 64u + l];
        const unsigned int u1 = xt8[d1 * 64u + l];
        const unsigned int u2 = xt8[d2 * 64u + l];
        const unsigned int u3 = xt8[d3 * 64u + l];
        ACC8(u0, s0);
        ACC8(u1, s1);
        ACC8(u2, s2);
        ACC8(u3, s3);
        ssum += (s0 + s1) + (s2 + s3);
    }
    for (; e < e1; ++e) {
        const unsigned long long ed = __builtin_nontemporal_load(edata + e);
        const unsigned d = (unsigned int)ed;
        const float w = __uint_as_float((unsigned int)(ed >> 32));
        const float s = edge_score(asrc, a_dst[d * 8u + h], w);
        const unsigned int u = xt8[d * 64u + l];
        ACC8(u, s);
        ssum += s;
    }
    const float inv = (e1 > e0) ? 1.f / ssum : 0.f;
    // residual add in fp32, round once to bf16
    const unsigned int xlo = (unsigned int)xin;
    const unsigned int xhi = (unsigned int)(xin >> 32);
    const float c0 = bf_lo(xlo) + fmaxf(a0 * inv, 0.f);
    const float c1 = bf_hi(xlo) + fmaxf(a1 * inv, 0.f);
    const float c2 = bf_lo(xhi) + fmaxf(a2 * inv, 0.f);
    const float c3 = bf_hi(xhi) + fmaxf(a3 * inv, 0.f);
    const unsigned long long pk =
        (unsigned long long)pack2bf(c0, c1) |
        ((unsigned long long)pack2bf(c2, c3) << 32);
    __builtin_nontemporal_store(pk, xrow);
}

// ---------------------------------------------------------------------------
extern "C" void kernel_launch(void* const* d_in, const int* in_sizes, int n_in,
                              void* d_out, int out_size, void* d_ws,
                              size_t ws_size, hipStream_t stream) {
    const float* node_states = (const float*)d_in[0];
    const int* edges = (const int*)d_in[1];
    const float* ew = (const float*)d_in[2];
    const float* Wp = (const float*)d_in[4];
    const float* bp = (const float*)d_in[5];
    const float* Wk = (const float*)d_in[6];
    const float* Wa = (const float*)d_in[7];
    const float* Wo = (const float*)d_in[8];
    const float* bo = (const float*)d_in[9];
    float* out = (float*)d_out;

    char* ws = (char*)d_ws;
    __hip_bfloat16* xb16 = (__hip_bfloat16*)ws; ws += (size_t)M_PAD * 256 * 2;     // 25.6 MB
    __hip_bfloat16* xt16 = (__hip_bfloat16*)ws; ws += (size_t)M_PAD * 256 * 2;     // 25.6 MB
    unsigned int* xt8 = (unsigned int*)ws;      ws += (size_t)M_PAD * 256;         // 12.8 MB
    int2* edata = (int2*)ws;                    ws += (size_t)NE * 8;              // 8 MB
    float* a_src = (float*)ws;                  ws += (size_t)M_PAD * N_HEADS * 4;
    float* a_dst = (float*)ws;                  ws += (size_t)M_PAD * N_HEADS * 4;
    __hip_bfloat16* wpT = (__hip_bfloat16*)ws;  ws += 65536 * 2;
    __hip_bfloat16* wkT = (__hip_bfloat16*)ws;  ws += 131072 * 2;
    __hip_bfloat16* woT = (__hip_bfloat16*)ws;  ws += 16384 * 2;
    int* row_st = (int*)ws;

    prep_kernel<<<17435, 256, 0, stream>>>(node_states, edges, ew, Wp, Wk, Wo,
                                           xt16, edata, wpT, wkT, woT, row_st);

    // xb16 = relu(ns @ Wp + bp)  (bf16 residual master)
    gemm_mfma<true, false, false><<<dim3((N_NODES + 127) / 128, 2), 256, 0,
                                    stream>>>(xt16, wpT, bp, xb16, nullptr,
                                              nullptr, nullptr);

    // layer 0: GEMM -> xt8 (fp8, coalesced stores) + fused alpha
    gemm_mfma<false, true, true><<<dim3((N_NODES + 127) / 128, 2), 256, 0,
                                   stream>>>(xb16, wkT, nullptr, xt8, Wa,
                                             a_src, a_dst);
    edge_kernel<<<N_NODES / 4, 256, 0, stream>>>(
        (const unsigned long long*)edata, row_st, xt8, a_src, a_dst, xb16);

    // layer 1
    gemm_mfma<false, true, true><<<dim3((N_NODES + 127) / 128, 2), 256, 0,
                                   stream>>>(xb16, wkT + 65536, nullptr, xt8,
                                             Wa + 512, a_src, a_dst);
    edge_kernel<<<N_NODES / 4, 256, 0, stream>>>(
        (const unsigned long long*)edata, row_st, xt8, a_src, a_dst, xb16);

    // out = xb16 @ Wo + bo (bf16 MFMA, fp32 store)
    gemm_mfma_out<<<(N_NODES + 127) / 128, 256, 0, stream>>>(xb16, woT, bo, out);
}

// Round 15
// 280.442 us; speedup vs baseline: 1.0828x; 1.0086x over previous
//
#include <hip/hip_runtime.h>
#include <hip/hip_bf16.h>
#include <math.h>

#define N_NODES 50000
#define F_DIM 256
#define NE 1000000
#define N_HEADS 8
#define M_PAD 50048   // 128-row padded

typedef __attribute__((ext_vector_type(8))) short short8;   // 8 bf16 = 4 VGPRs
typedef __attribute__((ext_vector_type(4))) float floatx4;
typedef __attribute__((ext_vector_type(2))) float floatx2;
typedef __attribute__((ext_vector_type(4))) unsigned int uintx4;

__device__ __forceinline__ void load16_lds(const void* g, void* l) {
    __builtin_amdgcn_global_load_lds(
        (const __attribute__((address_space(1))) unsigned int*)(unsigned long long)g,
        (__attribute__((address_space(3))) unsigned int*)(unsigned int)(unsigned long long)l,
        16, 0, 0);
}

__device__ __forceinline__ unsigned int pack2bf(float a, float b) {
    __hip_bfloat16 t0 = __float2bfloat16(a), t1 = __float2bfloat16(b);
    unsigned short u0, u1;
    __builtin_memcpy(&u0, &t0, 2);
    __builtin_memcpy(&u1, &t1, 2);
    return (unsigned int)u0 | ((unsigned int)u1 << 16);
}

__device__ __forceinline__ float bf_lo(unsigned int u) {
    return __uint_as_float(u << 16);
}
__device__ __forceinline__ float bf_hi(unsigned int u) {
    return __uint_as_float(u & 0xffff0000u);
}

// pack 4 fp32 -> 4 fp8 e4m3 (bytes 0..3), HW packed converters
__device__ __forceinline__ unsigned int pack4fp8(float x, float y, float z,
                                                 float w) {
    int v = __builtin_amdgcn_cvt_pk_fp8_f32(x, y, 0, false);   // bytes 0,1
    v = __builtin_amdgcn_cvt_pk_fp8_f32(z, w, v, true);        // bytes 2,3
    return (unsigned int)v;
}

// ---------------------------------------------------------------------------
// merged prep: blocks [0,3907) edata pack; [3907,4739) weight transpose+bf16;
// [4739,4935) row_start.  (conv_x removed: GEMM1 reads fp32 directly.)
// ---------------------------------------------------------------------------
__global__ __launch_bounds__(256) void prep_kernel(
    const int* __restrict__ edges, const float* __restrict__ ew,
    const float* __restrict__ Wp, const float* __restrict__ Wk,
    const float* __restrict__ Wo, int2* __restrict__ edata,
    __hip_bfloat16* __restrict__ wpT, __hip_bfloat16* __restrict__ wkT,
    __hip_bfloat16* __restrict__ woT, int* __restrict__ row_start) {
    const int b = blockIdx.x;
    const int tid = threadIdx.x;
    if (b < 3907) {                        // {dst, ew} pack
        const int e = b * 256 + tid;
        if (e < NE) {
            int2 d;
            d.x = edges[2 * e + 1];
            d.y = __float_as_int(ew[e]);
            edata[e] = d;
        }
    } else if (b < 4739) {                 // weights -> BT bf16
        const int wb = b - 3907;
        if (wb < 256) {
            int idx = wb * 256 + tid;          // 65536 = [n][k]
            int n = idx >> 8, k = idx & 255;
            wpT[idx] = __float2bfloat16(Wp[k * 256 + n]);
        } else if (wb < 768) {
            int idx = (wb - 256) * 256 + tid;  // 131072 = [l][n][k]
            int l = idx >> 16, n = (idx >> 8) & 255, k = idx & 255;
            int h = n >> 5, u = n & 31;
            wkT[idx] = __float2bfloat16(Wk[(((l * 8 + h) * 256) + k) * 32 + u]);
        } else {
            int idx = (wb - 768) * 256 + tid;  // 16384 = [n(64)][k(256)]
            int n = idx >> 8, k = idx & 255;
            woT[idx] = __float2bfloat16(Wo[k * 64 + n]);
        }
    } else {                               // row_start = lower_bound(src, i)
        const int i = (b - 4739) * 256 + tid;
        if (i > N_NODES) return;
        if (i == N_NODES) { row_start[N_NODES] = NE; return; }
        int lo = 0, hi = NE;
        while (lo < hi) {
            int mid = (lo + hi) >> 1;
            if (edges[2 * mid] < i) lo = mid + 1; else hi = mid;
        }
        row_start[i] = lo;
    }
}

// ---------------------------------------------------------------------------
// MFMA GEMM: Y[M x 256] = A[M x 256] @ B (BT as [256 n][256 k] bf16)
// 128x128 tile, 4 waves (2x2), 16x16x32 bf16 MFMA.
// K-loop: BK=64 as TWO 128x32 planes per tile -> 8 barriers.
// FP32A: A read as fp32 (node_states), converted in-register, ds_write into
// the identical LDS layout (rows clamped to N_NODES-1; stores guarded).
// FP8OUT: Y is fp8 e4m3 (xt8), stores coalesced via LDS transpose.
// ALPHA: emit a_src/a_dst from the fp32 accumulators.
// ---------------------------------------------------------------------------
template <bool BIAS_RELU, bool FP8OUT, bool ALPHA, bool FP32A>
__global__ __launch_bounds__(256) void gemm_mfma(
    const __hip_bfloat16* __restrict__ A16, const float* __restrict__ Af32,
    const __hip_bfloat16* __restrict__ BT, const float* __restrict__ bias,
    void* __restrict__ Y, const float* __restrict__ Wa_l,
    float* __restrict__ a_srcO, float* __restrict__ a_dstO) {
    __shared__ __align__(16) short lA[128 * 64];   // 2 planes of 128x32
    __shared__ __align__(16) short lB[128 * 64];
    const int tid = threadIdx.x;
    const int row0 = blockIdx.x * 128;
    const int n0 = blockIdx.y * 128;
    const int w = tid >> 6, l = tid & 63;
    const int wr = w >> 1, wc = w & 1;

    const __hip_bfloat16* gA =
        A16 + (size_t)(row0 + (tid >> 2)) * 256 + (tid & 3) * 8;
    const int r1 = min(row0 + (tid >> 2), N_NODES - 1);
    const int r2 = min(row0 + 64 + (tid >> 2), N_NODES - 1);
    const float* gAf1 = Af32 + (size_t)r1 * 256 + (tid & 3) * 8;
    const float* gAf2 = Af32 + (size_t)r2 * 256 + (tid & 3) * 8;
    const __hip_bfloat16* gB = BT + (size_t)(n0 + (tid >> 2)) * 256 + (tid & 3) * 8;
    short* dA = lA + tid * 8;
    short* dB = lB + tid * 8;

    floatx4 acc[4][4] = {};

    for (int kk = 0; kk < 4; ++kk) {
        const int ko = kk * 64;
#pragma unroll
        for (int p = 0; p < 2; ++p) {   // K-plane p covers cols ko+32p..+31
            if constexpr (FP32A) {
                const float4 v0 = *(const float4*)(gAf1 + ko + p * 32);
                const float4 v1 = *(const float4*)(gAf1 + ko + p * 32 + 4);
                uintx4 pk;
                pk.x = pack2bf(v0.x, v0.y);
                pk.y = pack2bf(v0.z, v0.w);
                pk.z = pack2bf(v1.x, v1.y);
                pk.w = pack2bf(v1.z, v1.w);
                *(uintx4*)(dA + p * 4096) = pk;
                const float4 u0 = *(const float4*)(gAf2 + ko + p * 32);
                const float4 u1 = *(const float4*)(gAf2 + ko + p * 32 + 4);
                uintx4 qk;
                qk.x = pack2bf(u0.x, u0.y);
                qk.y = pack2bf(u0.z, u0.w);
                qk.z = pack2bf(u1.x, u1.y);
                qk.w = pack2bf(u1.z, u1.w);
                *(uintx4*)(dA + p * 4096 + 2048) = qk;
            } else {
                load16_lds(gA + ko + p * 32, dA + p * 4096);
                load16_lds(gA + 64 * 256 + ko + p * 32, dA + p * 4096 + 2048);
            }
            load16_lds(gB + ko + p * 32, dB + p * 4096);
            load16_lds(gB + 64 * 256 + ko + p * 32, dB + p * 4096 + 2048);
        }
        __syncthreads();
#pragma unroll
        for (int kh = 0; kh < 2; ++kh) {
            const short* pa =
                lA + kh * 4096 + (wr * 64 + (l & 15)) * 32 + (l >> 4) * 8;
            const short* pb =
                lB + kh * 4096 + (wc * 64 + (l & 15)) * 32 + (l >> 4) * 8;
            short8 af[4], bf[4];
#pragma unroll
            for (int t = 0; t < 4; ++t) {
                af[t] = *(const short8*)(pa + t * 16 * 32);
                bf[t] = *(const short8*)(pb + t * 16 * 32);
            }
#pragma unroll
            for (int mt = 0; mt < 4; ++mt)
#pragma unroll
                for (int nt = 0; nt < 4; ++nt)
                    acc[mt][nt] = __builtin_amdgcn_mfma_f32_16x16x32_bf16(
                        bf[nt], af[mt], acc[mt][nt], 0, 0, 0);
        }
        __syncthreads();
    }

    const int m_base = row0 + wr * 64 + (l & 15);
    const int n_base = n0 + wc * 64 + ((l >> 4) << 2);

    if constexpr (ALPHA) {
        const int lg = l >> 4;
        float4 wS[2][2], wD[2][2];
#pragma unroll
        for (int hl = 0; hl < 2; ++hl) {
            const int h = (n0 >> 5) + wc * 2 + hl;
#pragma unroll
            for (int p = 0; p < 2; ++p) {
                wS[hl][p] = *(const float4*)(Wa_l + h * 64 + p * 16 + lg * 4);
                wD[hl][p] =
                    *(const float4*)(Wa_l + h * 64 + 32 + p * 16 + lg * 4);
            }
        }
        float aS[4][2], aD[4][2];
#pragma unroll
        for (int mt = 0; mt < 4; ++mt)
#pragma unroll
            for (int hl = 0; hl < 2; ++hl) {
                float s = 0.f, d = 0.f;
#pragma unroll
                for (int p = 0; p < 2; ++p) {
                    const floatx4 v = acc[mt][2 * hl + p];
                    const float4 ws = wS[hl][p], wd = wD[hl][p];
                    s += v.x * ws.x + v.y * ws.y + v.z * ws.z + v.w * ws.w;
                    d += v.x * wd.x + v.y * wd.y + v.z * wd.z + v.w * wd.w;
                }
                s += __shfl_xor(s, 16);
                s += __shfl_xor(s, 32);
                d += __shfl_xor(d, 16);
                d += __shfl_xor(d, 32);
                aS[mt][hl] = s;
                aD[mt][hl] = d;
            }
        if (lg == 0) {   // lanes 0..15: one writer per (m, h)
#pragma unroll
            for (int mt = 0; mt < 4; ++mt) {
                const int m = m_base + mt * 16;   // < M_PAD (buffers padded)
#pragma unroll
                for (int hl = 0; hl < 2; ++hl) {
                    const int h = (n0 >> 5) + wc * 2 + hl;
                    a_srcO[(size_t)m * 8 + h] = aS[mt][hl];
                    a_dstO[(size_t)m * 8 + h] = aD[mt][hl];
                }
            }
        }
    }

    if constexpr (FP8OUT) {
        // pack fp8 in-register, then LDS transpose -> coalesced dwordx4 rows
        unsigned int p8[4][4];
#pragma unroll
        for (int mt = 0; mt < 4; ++mt)
#pragma unroll
            for (int nt = 0; nt < 4; ++nt) {
                const floatx4 v = acc[mt][nt];
                p8[mt][nt] = pack4fp8(v.x, v.y, v.z, v.w);
            }
        unsigned int* lds32 = (unsigned int*)lA;   // 32 rows x 33 dwords (pad)
        const int row_local = wr * 16 + (l & 15);  // 0..31
        const int colb = wc * 16 + (l >> 4);       // dword col, +nt*4
        const int band = tid >> 7;                 // 0..1 (row half)
        const int rr = (tid >> 3) & 15;            // row within band
        const int dq = (tid & 7) << 2;             // dword col 0,4,..,28
        unsigned int* gout = (unsigned int*)Y +
                             (size_t)(row0 + band * 64) * 64 + (n0 >> 2) + dq;
#pragma unroll
        for (int mt = 0; mt < 4; ++mt) {
            __syncthreads();
#pragma unroll
            for (int nt = 0; nt < 4; ++nt)
                lds32[row_local * 33 + colb + nt * 4] = p8[mt][nt];
            __syncthreads();
            const unsigned int* src = lds32 + (band * 16 + rr) * 33 + dq;
            uintx4 o;
            o.x = src[0]; o.y = src[1]; o.z = src[2]; o.w = src[3];
            *(uintx4*)(gout + (size_t)(mt * 16 + rr) * 64) = o;
        }
    } else {
#pragma unroll
        for (int mt = 0; mt < 4; ++mt) {
            const int m = m_base + mt * 16;
            if (m >= N_NODES) continue;
#pragma unroll
            for (int nt = 0; nt < 4; ++nt) {
                const int n = n_base + nt * 16;
                floatx4 v = acc[mt][nt];
                if (BIAS_RELU) {
                    const float4 bb = *(const float4*)(bias + n);
                    v.x = fmaxf(v.x + bb.x, 0.f);
                    v.y = fmaxf(v.y + bb.y, 0.f);
                    v.z = fmaxf(v.z + bb.z, 0.f);
                    v.w = fmaxf(v.w + bb.w, 0.f);
                }
                uint2 pk;
                pk.x = pack2bf(v.x, v.y);
                pk.y = pack2bf(v.z, v.w);
                *(uint2*)((unsigned short*)Y + ((size_t)m << 8) + n) = pk;
            }
        }
    }
}

// ---------------------------------------------------------------------------
// Final projection: out[M x 64] = xb16[M x 256] @ Wo + bo  (fp32 out)
// BK=64 two-plane K-loop (4 barriers).
// ---------------------------------------------------------------------------
__global__ __launch_bounds__(256) void gemm_mfma_out(
    const __hip_bfloat16* __restrict__ A16, const __hip_bfloat16* __restrict__ BT,
    const float* __restrict__ bias, float* __restrict__ out) {
    __shared__ __align__(16) short lA[128 * 64];
    __shared__ __align__(16) short lB[64 * 64];
    const int tid = threadIdx.x;
    const int row0 = blockIdx.x * 128;
    const int w = tid >> 6, l = tid & 63;

    const __hip_bfloat16* gA = A16 + (size_t)(row0 + (tid >> 2)) * 256 + (tid & 3) * 8;
    const __hip_bfloat16* gB = BT + (size_t)(tid >> 2) * 256 + (tid & 3) * 8;
    short* dA = lA + tid * 8;
    short* dB = lB + tid * 8;   // 256 threads * 8 shorts = one 64x32 plane

    floatx4 acc[2][4] = {};

    for (int kk = 0; kk < 4; ++kk) {
        const int ko = kk * 64;
#pragma unroll
        for (int p = 0; p < 2; ++p) {
            load16_lds(gA + ko + p * 32, dA + p * 4096);
            load16_lds(gA + 64 * 256 + ko + p * 32, dA + p * 4096 + 2048);
            load16_lds(gB + ko + p * 32, dB + p * 2048);
        }
        __syncthreads();
#pragma unroll
        for (int kh = 0; kh < 2; ++kh) {
            const short* pa =
                lA + kh * 4096 + (w * 32 + (l & 15)) * 32 + (l >> 4) * 8;
            const short* pb = lB + kh * 2048 + (l & 15) * 32 + (l >> 4) * 8;
            short8 af[2], bf[4];
#pragma unroll
            for (int t = 0; t < 2; ++t)
                af[t] = *(const short8*)(pa + t * 16 * 32);
#pragma unroll
            for (int t = 0; t < 4; ++t)
                bf[t] = *(const short8*)(pb + t * 16 * 32);
#pragma unroll
            for (int mt = 0; mt < 2; ++mt)
#pragma unroll
                for (int nt = 0; nt < 4; ++nt)
                    acc[mt][nt] = __builtin_amdgcn_mfma_f32_16x16x32_bf16(
                        bf[nt], af[mt], acc[mt][nt], 0, 0, 0);
        }
        __syncthreads();
    }

    const int m_base = row0 + w * 32 + (l & 15);
    const int n_base = (l >> 4) << 2;
#pragma unroll
    for (int mt = 0; mt < 2; ++mt) {
        const int m = m_base + mt * 16;
        if (m >= N_NODES) continue;
#pragma unroll
        for (int nt = 0; nt < 4; ++nt) {
            const int n = n_base + nt * 16;
            const float4 bb = *(const float4*)(bias + n);
            floatx4 v = acc[mt][nt];
            float4 o = {v.x + bb.x, v.y + bb.y, v.z + bb.z, v.w + bb.w};
            *(float4*)(&out[(size_t)m * 64 + n]) = o;
        }
    }
}

// ---------------------------------------------------------------------------
// fused score + aggregation (R11 proven shape + 32-bit addressing):
// 1 wave per node (wave-uniform edge walk -> scalar bases), lane = 4 fp8
// features, 4-edge unroll. bf16 residual master xb16; streaming NT.
// ---------------------------------------------------------------------------
__device__ __forceinline__ float edge_score(float asrc, float ad, float w) {
    float sp = (asrc + ad) * w;
    sp = fmaxf(sp, 0.2f * sp);            // leaky_relu(0.2), branchless
    sp = fminf(fmaxf(sp, -2.f), 2.f);     // clip
    return __expf(sp);
}

#define ACC8(u, s)                                               \
    {                                                            \
        const floatx2 f01 = __builtin_amdgcn_cvt_pk_f32_fp8(u, false); \
        const floatx2 f23 = __builtin_amdgcn_cvt_pk_f32_fp8(u, true);  \
        a0 = fmaf(f01.x, s, a0);                                 \
        a1 = fmaf(f01.y, s, a1);                                 \
        a2 = fmaf(f23.x, s, a2);                                 \
        a3 = fmaf(f23.y, s, a3);                                 \
    }

__global__ __launch_bounds__(256) void edge_kernel(
    const unsigned long long* __restrict__ edata,
    const int* __restrict__ row_start, const unsigned int* __restrict__ xt8,
    const float* __restrict__ a_src, const float* __restrict__ a_dst,
    __hip_bfloat16* __restrict__ xb16) {
    const int tid = threadIdx.x;
    const int node =
        __builtin_amdgcn_readfirstlane(blockIdx.x * 4 + (tid >> 6));
    const unsigned l = (unsigned)(tid & 63);
    const unsigned h = l >> 3;
    const float asrc = a_src[(unsigned)node * 8u + h];
    const int e0 = __builtin_amdgcn_readfirstlane(row_start[node]);
    const int e1 = __builtin_amdgcn_readfirstlane(row_start[node + 1]);

    // residual row (bf16), non-temporal: streamed once per node
    unsigned long long* xrow =
        (unsigned long long*)((unsigned short*)xb16 + (size_t)node * 256 +
                              l * 4);
    const unsigned long long xin = __builtin_nontemporal_load(xrow);

    float a0 = 0.f, a1 = 0.f, a2 = 0.f, a3 = 0.f, ssum = 0.f;
    int e = e0;
    for (; e + 4 <= e1; e += 4) {
        const unsigned long long ed0 = __builtin_nontemporal_load(edata + e);
        const unsigned long long ed1 = __builtin_nontemporal_load(edata + e + 1);
        const unsigned long long ed2 = __builtin_nontemporal_load(edata + e + 2);
        const unsigned long long ed3 = __builtin_nontemporal_load(edata + e + 3);
        const unsigned d0 = (unsigned int)ed0;
        const unsigned d1 = (unsigned int)ed1;
        const unsigned d2 = (unsigned int)ed2;
        const unsigned d3 = (unsigned int)ed3;
        const float w0 = __uint_as_float((unsigned int)(ed0 >> 32));
        const float w1 = __uint_as_float((unsigned int)(ed1 >> 32));
        const float w2 = __uint_as_float((unsigned int)(ed2 >> 32));
        const float w3 = __uint_as_float((unsigned int)(ed3 >> 32));
        const float s0 = edge_score(asrc, a_dst[d0 * 8u + h], w0);
        const float s1 = edge_score(asrc, a_dst[d1 * 8u + h], w1);
        const float s2 = edge_score(asrc, a_dst[d2 * 8u + h], w2);
        const float s3 = edge_score(asrc, a_dst[d3 * 8u + h], w3);
        const unsigned int u0 = xt8[d0 * 64u + l];
        const unsigned int u1 = xt8[d1 * 64u + l];
        const unsigned int u2 = xt8[d2 * 64u + l];
        const unsigned int u3 = xt8[d3 * 64u + l];
        ACC8(u0, s0);
        ACC8(u1, s1);
        ACC8(u2, s2);
        ACC8(u3, s3);
        ssum += (s0 + s1) + (s2 + s3);
    }
    for (; e < e1; ++e) {
        const unsigned long long ed = __builtin_nontemporal_load(edata + e);
        const unsigned d = (unsigned int)ed;
        const float w = __uint_as_float((unsigned int)(ed >> 32));
        const float s = edge_score(asrc, a_dst[d * 8u + h], w);
        const unsigned int u = xt8[d * 64u + l];
        ACC8(u, s);
        ssum += s;
    }
    const float inv = (e1 > e0) ? 1.f / ssum : 0.f;
    // residual add in fp32, round once to bf16
    const unsigned int xlo = (unsigned int)xin;
    const unsigned int xhi = (unsigned int)(xin >> 32);
    const float c0 = bf_lo(xlo) + fmaxf(a0 * inv, 0.f);
    const float c1 = bf_hi(xlo) + fmaxf(a1 * inv, 0.f);
    const float c2 = bf_lo(xhi) + fmaxf(a2 * inv, 0.f);
    const float c3 = bf_hi(xhi) + fmaxf(a3 * inv, 0.f);
    const unsigned long long pk =
        (unsigned long long)pack2bf(c0, c1) |
        ((unsigned long long)pack2bf(c2, c3) << 32);
    __builtin_nontemporal_store(pk, xrow);
}

// ---------------------------------------------------------------------------
extern "C" void kernel_launch(void* const* d_in, const int* in_sizes, int n_in,
                              void* d_out, int out_size, void* d_ws,
                              size_t ws_size, hipStream_t stream) {
    const float* node_states = (const float*)d_in[0];
    const int* edges = (const int*)d_in[1];
    const float* ew = (const float*)d_in[2];
    const float* Wp = (const float*)d_in[4];
    const float* bp = (const float*)d_in[5];
    const float* Wk = (const float*)d_in[6];
    const float* Wa = (const float*)d_in[7];
    const float* Wo = (const float*)d_in[8];
    const float* bo = (const float*)d_in[9];
    float* out = (float*)d_out;

    char* ws = (char*)d_ws;
    __hip_bfloat16* xb16 = (__hip_bfloat16*)ws; ws += (size_t)M_PAD * 256 * 2;     // 25.6 MB
    unsigned int* xt8 = (unsigned int*)ws;      ws += (size_t)M_PAD * 256;         // 12.8 MB
    int2* edata = (int2*)ws;                    ws += (size_t)NE * 8;              // 8 MB
    float* a_src = (float*)ws;                  ws += (size_t)M_PAD * N_HEADS * 4;
    float* a_dst = (float*)ws;                  ws += (size_t)M_PAD * N_HEADS * 4;
    __hip_bfloat16* wpT = (__hip_bfloat16*)ws;  ws += 65536 * 2;
    __hip_bfloat16* wkT = (__hip_bfloat16*)ws;  ws += 131072 * 2;
    __hip_bfloat16* woT = (__hip_bfloat16*)ws;  ws += 16384 * 2;
    int* row_st = (int*)ws;

    prep_kernel<<<4935, 256, 0, stream>>>(edges, ew, Wp, Wk, Wo, edata, wpT,
                                          wkT, woT, row_st);

    // xb16 = relu(ns @ Wp + bp)  (fp32 A read + in-register bf16 convert)
    gemm_mfma<true, false, false, true>
        <<<dim3((N_NODES + 127) / 128, 2), 256, 0, stream>>>(
            nullptr, node_states, wpT, bp, xb16, nullptr, nullptr, nullptr);

    // layer 0: GEMM -> xt8 (fp8, coalesced stores) + fused alpha
    gemm_mfma<false, true, true, false>
        <<<dim3((N_NODES + 127) / 128, 2), 256, 0, stream>>>(
            xb16, nullptr, wkT, nullptr, xt8, Wa, a_src, a_dst);
    edge_kernel<<<N_NODES / 4, 256, 0, stream>>>(
        (const unsigned long long*)edata, row_st, xt8, a_src, a_dst, xb16);

    // layer 1
    gemm_mfma<false, true, true, false>
        <<<dim3((N_NODES + 127) / 128, 2), 256, 0, stream>>>(
            xb16, nullptr, wkT + 65536, nullptr, xt8, Wa + 512, a_src, a_dst);
    edge_kernel<<<N_NODES / 4, 256, 0, stream>>>(
        (const unsigned long long*)edata, row_st, xt8, a_src, a_dst, xb16);

    // out = xb16 @ Wo + bo (bf16 MFMA, fp32 store)
    gemm_mfma_out<<<(N_NODES + 127) / 128, 256, 0, stream>>>(xb16, woT, bo, out);
}